// Round 1
// baseline (102.177 us; speedup 1.0000x reference)
//
#include <hip/hip_runtime.h>
#include <hip/hip_bf16.h>
#include <math.h>

// Problem constants (from reference): B=8, N=128, D=128, C=32, H=256
#define BB 8
#define NN 128
#define DD 128
#define CC 32
#define HH 256
#define PP 16256            // N*(N-1)
#define ROWS (BB*NN)        // 1024
#define NBUCK 1024

// ws layout (floats):
//   Lp      : ROWS*HH  (x@W1[<128] + ctx@W1[256:288] + b1 folded in)
//   Rp      : ROWS*HH  (x@W1[128:256])
//   buckets : 2*NBUCK  ([0..NBUCK): weighted-bce partials, [NBUCK..): match partials)

// ---------------------------------------------------------------------------
// Kernel 1: per-row projections. 128 blocks x 256 threads, 8 rows/block.
// thread h in [0,256) owns output column h for all 8 rows.
// ---------------------------------------------------------------------------
__global__ __launch_bounds__(256) void k1_stage(
    const float* __restrict__ x, const float* __restrict__ ctx,
    const float* __restrict__ W1, const float* __restrict__ b1,
    float* __restrict__ Lp, float* __restrict__ Rp,
    float* __restrict__ buckets)
{
    __shared__ float xs[8 * DD];
    __shared__ float cs[CC];
    const int t  = threadIdx.x;
    const int r0 = blockIdx.x * 8;      // first row (b*N+n); 8 rows share batch b
    const int b  = r0 >> 7;

    // block 0 zeroes the reduction buckets (runs before k2 on the stream)
    if (blockIdx.x == 0) {
        for (int q = t; q < 2 * NBUCK; q += 256) buckets[q] = 0.f;
    }

    // cooperative load: 8 rows x 128 floats = 1024 floats = 256 float4
    ((float4*)xs)[t] = ((const float4*)(x + r0 * DD))[t];
    if (t < CC) cs[t] = ctx[b * CC + t];
    __syncthreads();

    const int h = t;
    float accL[8], accR[8];
#pragma unroll
    for (int r = 0; r < 8; ++r) { accL[r] = 0.f; accR[r] = 0.f; }

#pragma unroll 4
    for (int k = 0; k < DD; ++k) {
        const float wl = W1[k * HH + h];            // coalesced across h
        const float wr = W1[(k + DD) * HH + h];
#pragma unroll
        for (int r = 0; r < 8; ++r) {
            const float xv = xs[r * DD + k];        // LDS broadcast
            accL[r] = fmaf(xv, wl, accL[r]);
            accR[r] = fmaf(xv, wr, accR[r]);
        }
    }

    // fold context projection + b1 into L
    float cb = b1[h];
#pragma unroll 4
    for (int c = 0; c < CC; ++c) cb = fmaf(cs[c], W1[(2 * DD + c) * HH + h], cb);

#pragma unroll
    for (int r = 0; r < 8; ++r) {
        Lp[(r0 + r) * HH + h] = accL[r] + cb;
        Rp[(r0 + r) * HH + h] = accR[r];
    }
}

// ---------------------------------------------------------------------------
// Kernel 2: pair kernel. grid = ROWS*8 blocks x 256 threads.
// One wave handles one (b,i) with 4 consecutive j-slots (j in [0,128); j==i
// masked out). Lane l owns h-chunk [4l, 4l+4).
// ---------------------------------------------------------------------------
__global__ __launch_bounds__(256) void k2_pairs(
    const float* __restrict__ Lp, const float* __restrict__ Rp,
    const float* __restrict__ W2, const float* __restrict__ b2,
    const int* __restrict__ labels, const int* __restrict__ origin,
    float* __restrict__ pred, float* __restrict__ buckets)
{
    const int tid  = threadIdx.x;
    const int w    = tid >> 6;
    const int lane = tid & 63;
    const int bi   = blockIdx.x >> 3;       // b*N + i
    const int jb   = blockIdx.x & 7;
    const int b    = bi >> 7;
    const int i    = bi & 127;
    const int j0   = (jb * 4 + w) * 4;      // 0..124

    const float4 l4 = ((const float4*)(Lp + bi * HH))[lane];
    const float4 w4 = ((const float4*)W2)[lane];

    float a0, a1, a2, a3;
    {
        float at[4];
#pragma unroll
        for (int tt = 0; tt < 4; ++tt) {
            const float4 r4 = ((const float4*)(Rp + (b * NN + j0 + tt) * HH))[lane];
            float s;
            s = fmaxf(l4.x + r4.x, 0.f) * w4.x;
            s = fmaf(fmaxf(l4.y + r4.y, 0.f), w4.y, s);
            s = fmaf(fmaxf(l4.z + r4.z, 0.f), w4.z, s);
            s = fmaf(fmaxf(l4.w + r4.w, 0.f), w4.w, s);
            at[tt] = s;
        }
        // butterfly reduce each of the 4 partials across the full wave
#pragma unroll
        for (int m = 1; m < 64; m <<= 1) {
            at[0] += __shfl_xor(at[0], m, 64);
            at[1] += __shfl_xor(at[1], m, 64);
            at[2] += __shfl_xor(at[2], m, 64);
            at[3] += __shfl_xor(at[3], m, 64);
        }
        a0 = at[0]; a1 = at[1]; a2 = at[2]; a3 = at[3];
    }

    float bcew = 0.f, mt = 0.f;
    if (lane < 4) {
        const int j = j0 + lane;
        if (j != i) {
            float av = a0;
            av = (lane == 1) ? a1 : av;
            av = (lane == 2) ? a2 : av;
            av = (lane == 3) ? a3 : av;
            const float z = av + b2[0];
            const int pidx = b * PP + i * 127 + j - (j > i ? 1 : 0);
            pred[pidx] = z;

            const int li = labels[b * NN + i];
            const int lj = labels[b * NN + j];
            const float match = (li == lj && li >= 0) ? 1.f : 0.f;
            const int oi = origin[b * NN + i];
            const int oj = origin[b * NN + j];
            const int wi = (oi == 3 || oi == 4 || oi == 5) ? 1 : ((oi == 1) ? -1 : 0);
            const int wj = (oj == 3 || oj == 4 || oj == 5) ? 1 : ((oj == 1) ? -1 : 0);
            const float weight = (float)(1 + (wi & wj));   // {0,1,2}
            const float bce = fmaxf(z, 0.f) - z * match + log1pf(expf(-fabsf(z)));
            bcew = bce * weight;
            mt   = match;
        }
    }
    // sum lanes 0..3 into lane 0 (masks 1,2 only mix within groups of 4)
    bcew += __shfl_xor(bcew, 1, 64);
    bcew += __shfl_xor(bcew, 2, 64);
    mt   += __shfl_xor(mt, 1, 64);
    mt   += __shfl_xor(mt, 2, 64);
    if (lane == 0) {
        const int bkt = (int)((blockIdx.x * 4 + w) & (NBUCK - 1));
        atomicAdd(buckets + bkt, bcew);
        atomicAdd(buckets + NBUCK + bkt, mt);
    }
}

// ---------------------------------------------------------------------------
// Kernel 3: final loss = sum(bce*w) / sum(match). 1 block x 256 threads.
// ---------------------------------------------------------------------------
__global__ __launch_bounds__(256) void k3_final(
    const float* __restrict__ buckets, float* __restrict__ out_loss)
{
    __shared__ float sb[256], sm[256];
    const int t = threadIdx.x;
    float s1 = 0.f, s2 = 0.f;
    for (int q = t; q < NBUCK; q += 256) {
        s1 += buckets[q];
        s2 += buckets[NBUCK + q];
    }
    sb[t] = s1; sm[t] = s2;
    __syncthreads();
    for (int off = 128; off > 0; off >>= 1) {
        if (t < off) { sb[t] += sb[t + off]; sm[t] += sm[t + off]; }
        __syncthreads();
    }
    if (t == 0) out_loss[0] = sb[0] / sm[0];
}

extern "C" void kernel_launch(void* const* d_in, const int* in_sizes, int n_in,
                              void* d_out, int out_size, void* d_ws, size_t ws_size,
                              hipStream_t stream)
{
    const float* x      = (const float*)d_in[0];
    const float* ctx    = (const float*)d_in[1];
    const float* W1     = (const float*)d_in[2];
    const float* b1     = (const float*)d_in[3];
    const float* W2     = (const float*)d_in[4];
    const float* b2     = (const float*)d_in[5];
    const int*   labels = (const int*)d_in[6];
    const int*   origin = (const int*)d_in[7];

    float* pred = (float*)d_out;        // B*P floats
    float* loss = pred + BB * PP;       // 1 float

    float* Lp      = (float*)d_ws;
    float* Rp      = Lp + ROWS * HH;
    float* buckets = Rp + ROWS * HH;    // 2*NBUCK floats

    k1_stage<<<ROWS / 8, 256, 0, stream>>>(x, ctx, W1, b1, Lp, Rp, buckets);
    k2_pairs<<<ROWS * 8, 256, 0, stream>>>(Lp, Rp, W2, b2, labels, origin,
                                           pred, buckets);
    k3_final<<<1, 256, 0, stream>>>(buckets, loss);
}

// Round 3
// 101.897 us; speedup vs baseline: 1.0027x; 1.0027x over previous
//
#include <hip/hip_runtime.h>
#include <hip/hip_bf16.h>
#include <math.h>

// Problem constants: B=8, N=128, D=128, C=32, H=256
#define BB 8
#define NN 128
#define DD 128
#define CC 32
#define HH 256
#define PP 16256            // N*(N-1)
#define ROWS (BB*NN)        // 1024
#define NBUCK 64            // loss accumulation buckets (x2: bce, match)
#define TI 16
#define TJ 16
#define LPAD 260            // LDS row stride in floats (256 + 4 -> 16B pad)

// ws layout (floats):
//   Lp      : ROWS*HH   x@W1[0:128] + ctx@W1[256:288] + b1 folded in
//   Rp      : ROWS*HH   x@W1[128:256]
//   buckets : 128       [0..64) weighted-bce partials, [64..128) match partials
//   counter : 1 int     (at buckets[128], zeroed along with buckets)

// ---------------------------------------------------------------------------
// Kernel 1: per-row projections. 128 blocks x 256 threads, 8 rows/block.
// thread h owns output column h for all 8 rows. Also zeroes buckets+counter.
// ---------------------------------------------------------------------------
__global__ __launch_bounds__(256) void k1_stage(
    const float* __restrict__ x, const float* __restrict__ ctx,
    const float* __restrict__ W1, const float* __restrict__ b1,
    float* __restrict__ Lp, float* __restrict__ Rp,
    float* __restrict__ buckets)
{
    __shared__ float xs[8 * DD];
    __shared__ float cs[CC];
    const int t  = threadIdx.x;
    const int r0 = blockIdx.x * 8;      // 8 rows share batch b (N=128 multiple of 8)
    const int b  = r0 >> 7;

    // block 0 zeroes buckets (128 floats) + ticket counter (1 int at [128])
    if (blockIdx.x == 0 && t < 2 * NBUCK + 1) buckets[t] = 0.f;

    // cooperative load: 8 rows x 128 floats = 1024 floats = exactly 256 float4
    ((float4*)xs)[t] = ((const float4*)(x + r0 * DD))[t];
    if (t < CC) cs[t] = ctx[b * CC + t];
    __syncthreads();

    const int h = t;
    float accL[8], accR[8];
#pragma unroll
    for (int r = 0; r < 8; ++r) { accL[r] = 0.f; accR[r] = 0.f; }

#pragma unroll 4
    for (int k = 0; k < DD; ++k) {
        const float wl = W1[k * HH + h];            // coalesced across h
        const float wr = W1[(k + DD) * HH + h];
#pragma unroll
        for (int r = 0; r < 8; ++r) {
            const float xv = xs[r * DD + k];        // LDS broadcast
            accL[r] = fmaf(xv, wl, accL[r]);
            accR[r] = fmaf(xv, wr, accR[r]);
        }
    }

    float cb = b1[h];
#pragma unroll 4
    for (int c = 0; c < CC; ++c) cb = fmaf(cs[c], W1[(2 * DD + c) * HH + h], cb);

#pragma unroll
    for (int r = 0; r < 8; ++r) {
        Lp[(r0 + r) * HH + h] = accL[r] + cb;
        Rp[(r0 + r) * HH + h] = accR[r];
    }
}

// ---------------------------------------------------------------------------
// Kernel 2: pair kernel, GEMM-style tiling. 512 blocks x 256 threads.
// Block = (b, 16 i's, 16 j's); thread = one (i,j) pair, loops h in float4s.
// Last block to finish computes the final loss (coherent reads via atomicAdd).
// ---------------------------------------------------------------------------
__global__ __launch_bounds__(256) void k2_pairs(
    const float* __restrict__ Lp, const float* __restrict__ Rp,
    const float* __restrict__ W2, const float* __restrict__ b2,
    const int* __restrict__ labels, const int* __restrict__ origin,
    float* __restrict__ pred, float* __restrict__ buckets,
    int* __restrict__ counter, float* __restrict__ loss)
{
    __shared__ float Ls[TI][LPAD];
    __shared__ float Rs[TJ][LPAD];
    __shared__ float sred[8];
    __shared__ int amLast;

    const int tid = threadIdx.x;
    const int blk = blockIdx.x;
    const int b   = blk >> 6;
    const int i0  = ((blk >> 3) & 7) * TI;
    const int j0  = (blk & 7) * TJ;

    // stage tiles: 16 rows x 256 floats = 1024 float4 per tile -> 4 float4/thread
#pragma unroll
    for (int q = 0; q < 4; ++q) {
        const int idx = q * 256 + tid;          // [0,1024) float4 slots
        const int r   = idx >> 6;               // 64 float4 per row
        const int c4  = (idx & 63) * 4;
        *(float4*)(&Ls[r][c4]) = *(const float4*)(Lp + (b * NN + i0 + r) * HH + c4);
        *(float4*)(&Rs[r][c4]) = *(const float4*)(Rp + (b * NN + j0 + r) * HH + c4);
    }
    __syncthreads();

    const int ti = tid >> 4, tj = tid & 15;
    float4 acc = make_float4(0.f, 0.f, 0.f, 0.f);
#pragma unroll 8
    for (int hc = 0; hc < HH / 4; ++hc) {
        const float4 l = *(const float4*)(&Ls[ti][hc * 4]);   // 4-addr broadcast
        const float4 r = *(const float4*)(&Rs[tj][hc * 4]);   // <=2-way alias (free)
        const float4 w = ((const float4*)W2)[hc];             // wave-uniform -> scalar
        acc.x = fmaf(fmaxf(l.x + r.x, 0.f), w.x, acc.x);
        acc.y = fmaf(fmaxf(l.y + r.y, 0.f), w.y, acc.y);
        acc.z = fmaf(fmaxf(l.z + r.z, 0.f), w.z, acc.z);
        acc.w = fmaf(fmaxf(l.w + r.w, 0.f), w.w, acc.w);
    }

    const int i = i0 + ti, j = j0 + tj;
    float bcew = 0.f, mt = 0.f;
    if (i != j) {
        const float z = acc.x + acc.y + acc.z + acc.w + b2[0];
        pred[b * PP + i * 127 + j - (j > i ? 1 : 0)] = z;
        const int li = labels[b * NN + i], lj = labels[b * NN + j];
        const float match = (li == lj && li >= 0) ? 1.f : 0.f;
        const int oi = origin[b * NN + i], oj = origin[b * NN + j];
        const int wi = (oi == 3 || oi == 4 || oi == 5) ? 1 : ((oi == 1) ? -1 : 0);
        const int wj = (oj == 3 || oj == 4 || oj == 5) ? 1 : ((oj == 1) ? -1 : 0);
        const float weight = (float)(1 + (wi & wj));   // {0,1,2}
        bcew = (fmaxf(z, 0.f) - z * match + log1pf(expf(-fabsf(z)))) * weight;
        mt = match;
    }

    // block-level loss reduce: one wave butterfly per thread-block
#pragma unroll
    for (int m = 1; m < 64; m <<= 1) {
        bcew += __shfl_xor(bcew, m, 64);
        mt   += __shfl_xor(mt, m, 64);
    }
    const int w64 = tid >> 6, lane = tid & 63;
    if (lane == 0) { sred[w64] = bcew; sred[4 + w64] = mt; }
    __syncthreads();
    if (tid == 0) {
        const float s1 = sred[0] + sred[1] + sred[2] + sred[3];
        const float s2 = sred[4] + sred[5] + sred[6] + sred[7];
        const int bkt = blk & (NBUCK - 1);
        atomicAdd(buckets + bkt, s1);
        atomicAdd(buckets + NBUCK + bkt, s2);
        __threadfence();
        const int old = atomicAdd(counter, 1);
        amLast = (old == (int)gridDim.x - 1) ? 1 : 0;
    }
    __syncthreads();

    // last block computes loss = sum(bce*w)/sum(match).
    // Read buckets via atomicAdd(p,0) -> device-coherent (plain loads could hit
    // a stale per-XCD L2 line; L2s are not cross-coherent).
    if (amLast && tid < 64) {
        float v1 = atomicAdd(buckets + tid, 0.f);
        float v2 = atomicAdd(buckets + NBUCK + tid, 0.f);
#pragma unroll
        for (int m = 1; m < 64; m <<= 1) {
            v1 += __shfl_xor(v1, m, 64);
            v2 += __shfl_xor(v2, m, 64);
        }
        if (tid == 0) loss[0] = v1 / v2;
    }
}

extern "C" void kernel_launch(void* const* d_in, const int* in_sizes, int n_in,
                              void* d_out, int out_size, void* d_ws, size_t ws_size,
                              hipStream_t stream)
{
    const float* x      = (const float*)d_in[0];
    const float* ctx    = (const float*)d_in[1];
    const float* W1     = (const float*)d_in[2];
    const float* b1     = (const float*)d_in[3];
    const float* W2     = (const float*)d_in[4];
    const float* b2     = (const float*)d_in[5];
    const int*   labels = (const int*)d_in[6];
    const int*   origin = (const int*)d_in[7];

    float* pred = (float*)d_out;        // B*P floats
    float* loss = pred + BB * PP;       // 1 float

    float* Lp      = (float*)d_ws;
    float* Rp      = Lp + ROWS * HH;
    float* buckets = Rp + ROWS * HH;    // 128 floats + 1 int counter
    int*   counter = (int*)(buckets + 2 * NBUCK);

    k1_stage<<<ROWS / 8, 256, 0, stream>>>(x, ctx, W1, b1, Lp, Rp, buckets);
    k2_pairs<<<512, 256, 0, stream>>>(Lp, Rp, W2, b2, labels, origin,
                                      pred, buckets, counter, loss);
}